// Round 1
// baseline (711.483 us; speedup 1.0000x reference)
//
#include <hip/hip_runtime.h>

typedef unsigned short u16t;
typedef __attribute__((ext_vector_type(8))) short short8;
typedef __attribute__((ext_vector_type(4))) short short4v;
typedef __attribute__((ext_vector_type(4))) float f32x4;
typedef __attribute__((ext_vector_type(4))) unsigned short u16x4;

__device__ __forceinline__ float bf2f(short b) {
  return __uint_as_float(((unsigned)(unsigned short)b) << 16);
}
__device__ __forceinline__ u16t f2bf(float f) {
  unsigned u = __float_as_uint(f);
  u += 0x7FFFu + ((u >> 16) & 1u);  // RNE
  return (u16t)(u >> 16);
}

// jax threefry2x32, key = (0, 42)  [jax.random.key(42)]
// Partitionable counter scheme (JAX >= 0.4.36 default):
//   counter = flat index as u64 -> (hi=0, lo=flat); bits = o0 ^ o1
// keep = bits < 2^31  (uniform<0.5 for p=0.5)
__device__ __forceinline__ bool keep_mask(unsigned flat) {
  const unsigned k0 = 0u, k1 = 42u;
  const unsigned k2 = k0 ^ k1 ^ 0x1BD11BDAu;
  unsigned x0 = 0u + k0;
  unsigned x1 = flat + k1;
#define TF_R(r) { x0 += x1; x1 = (x1 << r) | (x1 >> (32 - r)); x1 ^= x0; }
  TF_R(13) TF_R(15) TF_R(26) TF_R(6)  x0 += k1; x1 += k2 + 1u;
  TF_R(17) TF_R(29) TF_R(16) TF_R(24) x0 += k2; x1 += k0 + 2u;
  TF_R(13) TF_R(15) TF_R(26) TF_R(6)  x0 += k0; x1 += k1 + 3u;
  TF_R(17) TF_R(29) TF_R(16) TF_R(24) x0 += k1; x1 += k2 + 4u;
  TF_R(13) TF_R(15) TF_R(26) TF_R(6)  x0 += k2; x1 += k0 + 5u;
#undef TF_R
  return ((x0 ^ x1) >> 31) == 0u;
}

__device__ __forceinline__ void load_lds16(const u16t* g, u16t* l) {
  __builtin_amdgcn_global_load_lds((__attribute__((address_space(1))) void*)g,
                                   (__attribute__((address_space(3))) void*)l,
                                   16, 0, 0);
}

// ---- f32 -> bf16 conversion (n divisible by 4) ----
__global__ void cvt_bf16(const float* __restrict__ s, u16t* __restrict__ d, int n) {
  int i = (blockIdx.x * 256 + threadIdx.x) * 4;
  if (i < n) {
    f32x4 v = *(const f32x4*)&s[i];
    u16x4 o = { f2bf(v.x), f2bf(v.y), f2bf(v.z), f2bf(v.w) };
    *(u16x4*)&d[i] = o;
  }
}

// ---- CSR build ----
__global__ void count_edges(const int* __restrict__ dst, int E, int* __restrict__ cnt) {
  int e = blockIdx.x * 256 + threadIdx.x;
  if (e < E) atomicAdd(&cnt[dst[e]], 1);
}

__global__ __launch_bounds__(1024) void scan_nodes(const int* __restrict__ cnt,
    int* __restrict__ rowp, int* __restrict__ cursor, float* __restrict__ dinv, int n) {
  __shared__ int sd[1024];
  __shared__ int sbase;
  const int tid = threadIdx.x;
  if (tid == 0) sbase = 0;
  for (int base = 0; base < n; base += 1024) {
    int idx = base + tid;
    int c = (idx < n) ? cnt[idx] : 0;
    int v = c;
    sd[tid] = v;
    __syncthreads();
    for (int offs = 1; offs < 1024; offs <<= 1) {
      int t = (tid >= offs) ? sd[tid - offs] : 0;
      __syncthreads();
      v += t;
      sd[tid] = v;
      __syncthreads();
    }
    int total = sd[1023];
    int b0 = sbase;
    if (idx < n) {
      int start = b0 + v - c;        // exclusive scan
      rowp[idx] = start;
      cursor[idx] = start;
      dinv[idx] = rsqrtf((float)(c + 1));  // +1 self loop
    }
    __syncthreads();
    if (tid == 0) sbase = b0 + total;
    __syncthreads();
  }
}

__global__ void fill_csr(const int* __restrict__ src, const int* __restrict__ dst, int E,
                         int* __restrict__ cursor, int* __restrict__ col) {
  int e = blockIdx.x * 256 + threadIdx.x;
  if (e < E) {
    int d = dst[e];
    int pos = atomicAdd(&cursor[d], 1);
    col[pos] = src[e];
  }
  // after this kernel, cursor[i] == row end offset
}

// ---- m97-style bf16 GEMM: C[m,n] = sum_k A[m,k]*B[n,k]; A[M,K], B[N,K], C bf16 [M,Ncols]
__global__ __launch_bounds__(256) void gemm_bt(const u16t* __restrict__ A,
                                               const u16t* __restrict__ B,
                                               u16t* __restrict__ C,
                                               int K, int Ncols) {
  __shared__ __align__(16) u16t lA[128 * 32];
  __shared__ __align__(16) u16t lB[128 * 32];
  const int tid = threadIdx.x;
  const int wave = tid >> 6, lane = tid & 63;
  const int wm = (wave & 1) * 64, wn = (wave >> 1) * 64;
  const int lrow = lane & 15, lq = lane >> 4;
  const u16t* Ab = A + (size_t)blockIdx.x * 128 * K;
  const u16t* Bb = B + (size_t)blockIdx.y * 128 * K;
  const int r0 = tid >> 2, c0 = (tid & 3) * 8;
  const int ldsOff = __builtin_amdgcn_readfirstlane((tid >> 6) * 512);

  f32x4 acc[4][4];
  const f32x4 zero = {0.f, 0.f, 0.f, 0.f};
#pragma unroll
  for (int mi = 0; mi < 4; ++mi)
#pragma unroll
    for (int ni = 0; ni < 4; ++ni) acc[mi][ni] = zero;

  for (int kt = 0; kt < K; kt += 32) {
    __syncthreads();
    load_lds16(Ab + (size_t)r0 * K + kt + c0, &lA[ldsOff]);
    load_lds16(Ab + (size_t)(r0 + 64) * K + kt + c0, &lA[2048 + ldsOff]);
    load_lds16(Bb + (size_t)r0 * K + kt + c0, &lB[ldsOff]);
    load_lds16(Bb + (size_t)(r0 + 64) * K + kt + c0, &lB[2048 + ldsOff]);
    __syncthreads();
    short8 af[4], bfr[4];
#pragma unroll
    for (int mi = 0; mi < 4; ++mi)
      af[mi] = *(const short8*)&lA[(wm + mi * 16 + lrow) * 32 + lq * 8];
#pragma unroll
    for (int ni = 0; ni < 4; ++ni)
      bfr[ni] = *(const short8*)&lB[(wn + ni * 16 + lrow) * 32 + lq * 8];
#pragma unroll
    for (int mi = 0; mi < 4; ++mi)
#pragma unroll
      for (int ni = 0; ni < 4; ++ni)
        acc[mi][ni] = __builtin_amdgcn_mfma_f32_16x16x32_bf16(af[mi], bfr[ni], acc[mi][ni], 0, 0, 0);
  }

  const size_t crow = (size_t)blockIdx.x * 128 + wm + lq * 4;
  const int ccol = blockIdx.y * 128 + wn + lrow;
#pragma unroll
  for (int mi = 0; mi < 4; ++mi)
#pragma unroll
    for (int r = 0; r < 4; ++r)
#pragma unroll
      for (int ni = 0; ni < 4; ++ni)
        C[(crow + mi * 16 + r) * Ncols + ccol + ni * 16] = f2bf(acc[mi][ni][r]);
}

// ---- propagate layer 1 + bias + relu + dropout; writes emb f32 (d_out) + emb bf16 (ws)
__global__ __launch_bounds__(256) void prop1_kernel(const u16t* __restrict__ y1,
    const int* __restrict__ col, const int* __restrict__ rowp, const int* __restrict__ rowend,
    const float* __restrict__ dinv, const float* __restrict__ b1,
    float* __restrict__ embf, u16t* __restrict__ embb, int n) {
  const int lane = threadIdx.x & 63;
  const int i = blockIdx.x * 4 + (threadIdx.x >> 6);
  if (i >= n) return;
  const int f = lane * 8;
  const float di = dinv[i];
  float acc[8];
  short8 v = *(const short8*)&y1[(size_t)i * 512 + f];
#pragma unroll
  for (int j = 0; j < 8; ++j) acc[j] = di * bf2f(v[j]);
  const int e0 = rowp[i], e1 = rowend[i];
  for (int e = e0; e < e1; ++e) {
    const int s = col[e];
    const float w = dinv[s];
    short8 u = *(const short8*)&y1[(size_t)s * 512 + f];
#pragma unroll
    for (int j = 0; j < 8; ++j) acc[j] += w * bf2f(u[j]);
  }
  const unsigned flat = (unsigned)i * 512u + (unsigned)f;
  f32x4 o0, o1;
  short8 ob;
#pragma unroll
  for (int j = 0; j < 8; ++j) {
    float h = di * acc[j] + b1[f + j];
    h = fmaxf(h, 0.f);
    float eb = keep_mask(flat + (unsigned)j) ? 2.f * h : 0.f;
    if (j < 4) o0[j] = eb; else o1[j - 4] = eb;
    ob[j] = (short)f2bf(eb);
  }
  *(f32x4*)&embf[(size_t)i * 512 + f] = o0;
  *(f32x4*)&embf[(size_t)i * 512 + f + 4] = o1;
  *(short8*)&embb[(size_t)i * 512 + f] = ob;
}

// ---- propagate layer 2 + bias; writes out f32
__global__ __launch_bounds__(256) void prop2_kernel(const u16t* __restrict__ z,
    const int* __restrict__ col, const int* __restrict__ rowp, const int* __restrict__ rowend,
    const float* __restrict__ dinv, const float* __restrict__ b2,
    float* __restrict__ outp, int n) {
  const int lane = threadIdx.x & 63;
  const int i = blockIdx.x * 4 + (threadIdx.x >> 6);
  if (i >= n) return;
  const int f = lane * 4;
  const float di = dinv[i];
  float acc[4];
  short4v v = *(const short4v*)&z[(size_t)i * 256 + f];
#pragma unroll
  for (int j = 0; j < 4; ++j) acc[j] = di * bf2f(v[j]);
  const int e0 = rowp[i], e1 = rowend[i];
  for (int e = e0; e < e1; ++e) {
    const int s = col[e];
    const float w = dinv[s];
    short4v u = *(const short4v*)&z[(size_t)s * 256 + f];
#pragma unroll
    for (int j = 0; j < 4; ++j) acc[j] += w * bf2f(u[j]);
  }
  f32x4 o;
#pragma unroll
  for (int j = 0; j < 4; ++j) o[j] = di * acc[j] + b2[f + j];
  *(f32x4*)&outp[(size_t)i * 256 + f] = o;
}

extern "C" void kernel_launch(void* const* d_in, const int* in_sizes, int n_in,
                              void* d_out, int out_size, void* d_ws, size_t ws_size,
                              hipStream_t stream) {
  (void)n_in; (void)out_size; (void)ws_size;
  const float* x  = (const float*)d_in[0];
  const int*   ei = (const int*)d_in[1];    // [2][E]: src row then dst row
  const float* W1 = (const float*)d_in[2];
  const float* b1 = (const float*)d_in[3];
  const float* W2 = (const float*)d_in[4];
  const float* b2 = (const float*)d_in[5];

  const int Nn = in_sizes[0] / 512;             // 50000
  const int E  = in_sizes[1] / 2;               // 800000
  const int Mpad = ((Nn + 127) / 128) * 128;    // 50048
  const int K = 512;

  char* ws = (char*)d_ws;
  size_t off = 0;
  auto take = [&](size_t bytes) -> char* {
    char* p = ws + off;
    off += (bytes + 255) & ~(size_t)255;
    return p;
  };
  u16t* xb   = (u16t*)take((size_t)Mpad * 512 * 2);  // x bf16; later reused as emb bf16
  u16t* y1b  = (u16t*)take((size_t)Mpad * 512 * 2);  // y1 = x@W1^T bf16; later reused as z
  u16t* W1b  = (u16t*)take((size_t)512 * 512 * 2);
  u16t* W2b  = (u16t*)take((size_t)256 * 512 * 2);
  int*   cnt    = (int*)take((size_t)Nn * 4);
  int*   rowp   = (int*)take((size_t)Nn * 4);
  int*   cursor = (int*)take((size_t)Nn * 4);
  float* dinv   = (float*)take((size_t)Nn * 4);
  int*   colA   = (int*)take((size_t)E * 4);

  float* embf = (float*)d_out;                       // [Nn,512]
  float* outf = (float*)d_out + (size_t)Nn * 512;    // [Nn,256]

  hipMemsetAsync(cnt, 0, (size_t)Nn * 4, stream);

  const int n1 = Nn * 512;
  cvt_bf16<<<(n1 / 4 + 255) / 256, 256, 0, stream>>>(x, xb, n1);
  cvt_bf16<<<(512 * 512 / 4 + 255) / 256, 256, 0, stream>>>(W1, W1b, 512 * 512);
  cvt_bf16<<<(256 * 512 / 4 + 255) / 256, 256, 0, stream>>>(W2, W2b, 256 * 512);

  count_edges<<<(E + 255) / 256, 256, 0, stream>>>(ei + E, E, cnt);
  scan_nodes<<<1, 1024, 0, stream>>>(cnt, rowp, cursor, dinv, Nn);
  fill_csr<<<(E + 255) / 256, 256, 0, stream>>>(ei, ei + E, E, cursor, colA);

  // layer 1: y1 = x @ W1^T (bf16), then out-of-order propagate (P commutes with right-mul)
  dim3 g1(Mpad / 128, 4);
  gemm_bt<<<g1, 256, 0, stream>>>(xb, W1b, y1b, K, 512);
  prop1_kernel<<<(Nn + 3) / 4, 256, 0, stream>>>(y1b, colA, rowp, cursor, dinv, b1,
                                                 embf, xb /* emb bf16, aliases xb */, Nn);

  // layer 2: z = emb @ W2^T (bf16), then propagate + b2
  u16t* zb = y1b;  // alias: y1 dead after prop1
  dim3 g2(Mpad / 128, 2);
  gemm_bt<<<g2, 256, 0, stream>>>(xb, W2b, zb, K, 256);
  prop2_kernel<<<(Nn + 3) / 4, 256, 0, stream>>>(zb, colA, rowp, cursor, dinv, b2, outf, Nn);
}

// Round 2
// 590.873 us; speedup vs baseline: 1.2041x; 1.2041x over previous
//
#include <hip/hip_runtime.h>

typedef unsigned short u16t;
typedef __attribute__((ext_vector_type(8))) short short8;
typedef __attribute__((ext_vector_type(4))) short short4v;
typedef __attribute__((ext_vector_type(4))) float f32x4;
typedef __attribute__((ext_vector_type(4))) unsigned short u16x4;

__device__ __forceinline__ float bf2f(short b) {
  return __uint_as_float(((unsigned)(unsigned short)b) << 16);
}
__device__ __forceinline__ u16t f2bf(float f) {
  unsigned u = __float_as_uint(f);
  u += 0x7FFFu + ((u >> 16) & 1u);  // RNE
  return (u16t)(u >> 16);
}

// jax threefry2x32, key = (0, 42); partitionable counter scheme:
// counter = flat u64 -> (hi=0, lo=flat); bits = o0 ^ o1; keep = top bit 0 (p=0.5)
__device__ __forceinline__ bool keep_mask(unsigned flat) {
  const unsigned k0 = 0u, k1 = 42u;
  const unsigned k2 = k0 ^ k1 ^ 0x1BD11BDAu;
  unsigned x0 = 0u + k0;
  unsigned x1 = flat + k1;
#define TF_R(r) { x0 += x1; x1 = (x1 << r) | (x1 >> (32 - r)); x1 ^= x0; }
  TF_R(13) TF_R(15) TF_R(26) TF_R(6)  x0 += k1; x1 += k2 + 1u;
  TF_R(17) TF_R(29) TF_R(16) TF_R(24) x0 += k2; x1 += k0 + 2u;
  TF_R(13) TF_R(15) TF_R(26) TF_R(6)  x0 += k0; x1 += k1 + 3u;
  TF_R(17) TF_R(29) TF_R(16) TF_R(24) x0 += k1; x1 += k2 + 4u;
  TF_R(13) TF_R(15) TF_R(26) TF_R(6)  x0 += k2; x1 += k0 + 5u;
#undef TF_R
  return ((x0 ^ x1) >> 31) == 0u;
}

__device__ __forceinline__ void load_lds16(const u16t* g, u16t* l) {
  __builtin_amdgcn_global_load_lds((__attribute__((address_space(1))) void*)g,
                                   (__attribute__((address_space(3))) void*)l,
                                   16, 0, 0);
}

// ---- f32 -> bf16 conversion (n divisible by 4) ----
__global__ void cvt_bf16(const float* __restrict__ s, u16t* __restrict__ d, int n) {
  int i = (blockIdx.x * 256 + threadIdx.x) * 4;
  if (i < n) {
    f32x4 v = *(const f32x4*)&s[i];
    u16x4 o = { f2bf(v.x), f2bf(v.y), f2bf(v.z), f2bf(v.w) };
    *(u16x4*)&d[i] = o;
  }
}

// ---- CSR build ----
__global__ void count_edges(const int* __restrict__ dst, int E, int* __restrict__ cnt) {
  int e = blockIdx.x * 256 + threadIdx.x;
  if (e < E) atomicAdd(&cnt[dst[e]], 1);
}

// Parallel row-pointer build: block-local exclusive scan + one global atomic per
// block. Row ranges land in nondeterministic order across the col array, but
// each node's [rowp, rowend) slice is private, so results are identical.
__global__ __launch_bounds__(256) void rowp_build(const int* __restrict__ cnt,
    int* __restrict__ rowp, int* __restrict__ cursor, float* __restrict__ dinv,
    int* __restrict__ gctr, int n) {
  __shared__ int sd[256];
  __shared__ int sbase;
  const int tid = threadIdx.x;
  const int i = blockIdx.x * 256 + tid;
  int c = (i < n) ? cnt[i] : 0;
  int v = c;
  sd[tid] = v;
  __syncthreads();
  for (int o = 1; o < 256; o <<= 1) {
    int t = (tid >= o) ? sd[tid - o] : 0;
    __syncthreads();
    v += t;
    sd[tid] = v;
    __syncthreads();
  }
  if (tid == 255) sbase = atomicAdd(gctr, v);  // v == block total (inclusive scan last)
  __syncthreads();
  if (i < n) {
    int start = sbase + v - c;  // exclusive scan within block + block base
    rowp[i] = start;
    cursor[i] = start;
    dinv[i] = rsqrtf((float)(c + 1));  // +1 self loop
  }
}

__global__ void fill_csr(const int* __restrict__ src, const int* __restrict__ dst, int E,
                         int* __restrict__ cursor, int* __restrict__ col) {
  int e = blockIdx.x * 256 + threadIdx.x;
  if (e < E) {
    int d = dst[e];
    int pos = atomicAdd(&cursor[d], 1);
    col[pos] = src[e];
  }
  // after this kernel, cursor[i] == row end offset
}

// ---- m97-style bf16 GEMM: C[m,n] = sum_k A[m,k]*B[n,k]; A[M,K], B[N,K], C bf16 [M,Ncols]
__global__ __launch_bounds__(256) void gemm_bt(const u16t* __restrict__ A,
                                               const u16t* __restrict__ B,
                                               u16t* __restrict__ C,
                                               int K, int Ncols) {
  __shared__ __align__(16) u16t lA[128 * 32];
  __shared__ __align__(16) u16t lB[128 * 32];
  const int tid = threadIdx.x;
  const int wave = tid >> 6, lane = tid & 63;
  const int wm = (wave & 1) * 64, wn = (wave >> 1) * 64;
  const int lrow = lane & 15, lq = lane >> 4;
  const u16t* Ab = A + (size_t)blockIdx.x * 128 * K;
  const u16t* Bb = B + (size_t)blockIdx.y * 128 * K;
  const int r0 = tid >> 2, c0 = (tid & 3) * 8;
  const int ldsOff = __builtin_amdgcn_readfirstlane((tid >> 6) * 512);

  f32x4 acc[4][4];
  const f32x4 zero = {0.f, 0.f, 0.f, 0.f};
#pragma unroll
  for (int mi = 0; mi < 4; ++mi)
#pragma unroll
    for (int ni = 0; ni < 4; ++ni) acc[mi][ni] = zero;

  for (int kt = 0; kt < K; kt += 32) {
    __syncthreads();
    load_lds16(Ab + (size_t)r0 * K + kt + c0, &lA[ldsOff]);
    load_lds16(Ab + (size_t)(r0 + 64) * K + kt + c0, &lA[2048 + ldsOff]);
    load_lds16(Bb + (size_t)r0 * K + kt + c0, &lB[ldsOff]);
    load_lds16(Bb + (size_t)(r0 + 64) * K + kt + c0, &lB[2048 + ldsOff]);
    __syncthreads();
    short8 af[4], bfr[4];
#pragma unroll
    for (int mi = 0; mi < 4; ++mi)
      af[mi] = *(const short8*)&lA[(wm + mi * 16 + lrow) * 32 + lq * 8];
#pragma unroll
    for (int ni = 0; ni < 4; ++ni)
      bfr[ni] = *(const short8*)&lB[(wn + ni * 16 + lrow) * 32 + lq * 8];
#pragma unroll
    for (int mi = 0; mi < 4; ++mi)
#pragma unroll
      for (int ni = 0; ni < 4; ++ni)
        acc[mi][ni] = __builtin_amdgcn_mfma_f32_16x16x32_bf16(af[mi], bfr[ni], acc[mi][ni], 0, 0, 0);
  }

  const size_t crow = (size_t)blockIdx.x * 128 + wm + lq * 4;
  const int ccol = blockIdx.y * 128 + wn + lrow;
#pragma unroll
  for (int mi = 0; mi < 4; ++mi)
#pragma unroll
    for (int r = 0; r < 4; ++r)
#pragma unroll
      for (int ni = 0; ni < 4; ++ni)
        C[(crow + mi * 16 + r) * Ncols + ccol + ni * 16] = f2bf(acc[mi][ni][r]);
}

// ---- propagate layer 1 + bias + relu + dropout; writes emb f32 (d_out) + emb bf16 (ws)
// 4-way unrolled gather: 4 independent 1KB row loads in flight per wave.
__global__ __launch_bounds__(256) void prop1_kernel(const u16t* __restrict__ y1,
    const int* __restrict__ col, const int* __restrict__ rowp, const int* __restrict__ rowend,
    const float* __restrict__ dinv, const float* __restrict__ b1,
    float* __restrict__ embf, u16t* __restrict__ embb, int n) {
  const int lane = threadIdx.x & 63;
  const int i = blockIdx.x * 4 + (threadIdx.x >> 6);
  if (i >= n) return;
  const int f = lane * 8;
  const float di = dinv[i];
  float acc[8];
  short8 v = *(const short8*)&y1[(size_t)i * 512 + f];
#pragma unroll
  for (int j = 0; j < 8; ++j) acc[j] = di * bf2f(v[j]);
  int e = rowp[i];
  const int e1 = rowend[i];
  for (; e + 4 <= e1; e += 4) {
    const int s0 = col[e], s1 = col[e + 1], s2 = col[e + 2], s3 = col[e + 3];
    const float w0 = dinv[s0], w1 = dinv[s1], w2 = dinv[s2], w3 = dinv[s3];
    short8 u0 = *(const short8*)&y1[(size_t)s0 * 512 + f];
    short8 u1 = *(const short8*)&y1[(size_t)s1 * 512 + f];
    short8 u2 = *(const short8*)&y1[(size_t)s2 * 512 + f];
    short8 u3 = *(const short8*)&y1[(size_t)s3 * 512 + f];
#pragma unroll
    for (int j = 0; j < 8; ++j) acc[j] += w0 * bf2f(u0[j]);
#pragma unroll
    for (int j = 0; j < 8; ++j) acc[j] += w1 * bf2f(u1[j]);
#pragma unroll
    for (int j = 0; j < 8; ++j) acc[j] += w2 * bf2f(u2[j]);
#pragma unroll
    for (int j = 0; j < 8; ++j) acc[j] += w3 * bf2f(u3[j]);
  }
  for (; e < e1; ++e) {
    const int s = col[e];
    const float w = dinv[s];
    short8 u = *(const short8*)&y1[(size_t)s * 512 + f];
#pragma unroll
    for (int j = 0; j < 8; ++j) acc[j] += w * bf2f(u[j]);
  }
  const unsigned flat = (unsigned)i * 512u + (unsigned)f;
  f32x4 o0, o1;
  short8 ob;
#pragma unroll
  for (int j = 0; j < 8; ++j) {
    float h = di * acc[j] + b1[f + j];
    h = fmaxf(h, 0.f);
    float eb = keep_mask(flat + (unsigned)j) ? 2.f * h : 0.f;
    if (j < 4) o0[j] = eb; else o1[j - 4] = eb;
    ob[j] = (short)f2bf(eb);
  }
  *(f32x4*)&embf[(size_t)i * 512 + f] = o0;
  *(f32x4*)&embf[(size_t)i * 512 + f + 4] = o1;
  *(short8*)&embb[(size_t)i * 512 + f] = ob;
}

// ---- propagate layer 2 + bias; writes out f32 (4-way unrolled gather)
__global__ __launch_bounds__(256) void prop2_kernel(const u16t* __restrict__ z,
    const int* __restrict__ col, const int* __restrict__ rowp, const int* __restrict__ rowend,
    const float* __restrict__ dinv, const float* __restrict__ b2,
    float* __restrict__ outp, int n) {
  const int lane = threadIdx.x & 63;
  const int i = blockIdx.x * 4 + (threadIdx.x >> 6);
  if (i >= n) return;
  const int f = lane * 4;
  const float di = dinv[i];
  float acc[4];
  short4v v = *(const short4v*)&z[(size_t)i * 256 + f];
#pragma unroll
  for (int j = 0; j < 4; ++j) acc[j] = di * bf2f(v[j]);
  int e = rowp[i];
  const int e1 = rowend[i];
  for (; e + 4 <= e1; e += 4) {
    const int s0 = col[e], s1 = col[e + 1], s2 = col[e + 2], s3 = col[e + 3];
    const float w0 = dinv[s0], w1 = dinv[s1], w2 = dinv[s2], w3 = dinv[s3];
    short4v u0 = *(const short4v*)&z[(size_t)s0 * 256 + f];
    short4v u1 = *(const short4v*)&z[(size_t)s1 * 256 + f];
    short4v u2 = *(const short4v*)&z[(size_t)s2 * 256 + f];
    short4v u3 = *(const short4v*)&z[(size_t)s3 * 256 + f];
#pragma unroll
    for (int j = 0; j < 4; ++j) acc[j] += w0 * bf2f(u0[j]);
#pragma unroll
    for (int j = 0; j < 4; ++j) acc[j] += w1 * bf2f(u1[j]);
#pragma unroll
    for (int j = 0; j < 4; ++j) acc[j] += w2 * bf2f(u2[j]);
#pragma unroll
    for (int j = 0; j < 4; ++j) acc[j] += w3 * bf2f(u3[j]);
  }
  for (; e < e1; ++e) {
    const int s = col[e];
    const float w = dinv[s];
    short4v u = *(const short4v*)&z[(size_t)s * 256 + f];
#pragma unroll
    for (int j = 0; j < 4; ++j) acc[j] += w * bf2f(u[j]);
  }
  f32x4 o;
#pragma unroll
  for (int j = 0; j < 4; ++j) o[j] = di * acc[j] + b2[f + j];
  *(f32x4*)&outp[(size_t)i * 256 + f] = o;
}

extern "C" void kernel_launch(void* const* d_in, const int* in_sizes, int n_in,
                              void* d_out, int out_size, void* d_ws, size_t ws_size,
                              hipStream_t stream) {
  (void)n_in; (void)out_size; (void)ws_size;
  const float* x  = (const float*)d_in[0];
  const int*   ei = (const int*)d_in[1];    // [2][E]: src row then dst row
  const float* W1 = (const float*)d_in[2];
  const float* b1 = (const float*)d_in[3];
  const float* W2 = (const float*)d_in[4];
  const float* b2 = (const float*)d_in[5];

  const int Nn = in_sizes[0] / 512;             // 50000
  const int E  = in_sizes[1] / 2;               // 800000
  const int Mpad = ((Nn + 127) / 128) * 128;    // 50048
  const int K = 512;

  char* ws = (char*)d_ws;
  size_t off = 0;
  auto take = [&](size_t bytes) -> char* {
    char* p = ws + off;
    off += (bytes + 255) & ~(size_t)255;
    return p;
  };
  u16t* xb   = (u16t*)take((size_t)Mpad * 512 * 2);  // x bf16; later reused as emb bf16
  u16t* y1b  = (u16t*)take((size_t)Mpad * 512 * 2);  // y1 = x@W1^T bf16; later reused as z
  u16t* W1b  = (u16t*)take((size_t)512 * 512 * 2);
  u16t* W2b  = (u16t*)take((size_t)256 * 512 * 2);
  int*   cnt    = (int*)take((size_t)(Nn + 1) * 4);  // cnt[Nn] is the global cursor
  int*   rowp   = (int*)take((size_t)Nn * 4);
  int*   cursor = (int*)take((size_t)Nn * 4);
  float* dinv   = (float*)take((size_t)Nn * 4);
  int*   colA   = (int*)take((size_t)E * 4);

  float* embf = (float*)d_out;                       // [Nn,512]
  float* outf = (float*)d_out + (size_t)Nn * 512;    // [Nn,256]

  hipMemsetAsync(cnt, 0, (size_t)(Nn + 1) * 4, stream);

  const int n1 = Nn * 512;
  cvt_bf16<<<(n1 / 4 + 255) / 256, 256, 0, stream>>>(x, xb, n1);
  cvt_bf16<<<(512 * 512 / 4 + 255) / 256, 256, 0, stream>>>(W1, W1b, 512 * 512);
  cvt_bf16<<<(256 * 512 / 4 + 255) / 256, 256, 0, stream>>>(W2, W2b, 256 * 512);

  count_edges<<<(E + 255) / 256, 256, 0, stream>>>(ei + E, E, cnt);
  rowp_build<<<(Nn + 255) / 256, 256, 0, stream>>>(cnt, rowp, cursor, dinv, cnt + Nn, Nn);
  fill_csr<<<(E + 255) / 256, 256, 0, stream>>>(ei, ei + E, E, cursor, colA);

  // layer 1: y1 = x @ W1^T (bf16), then out-of-order propagate (P commutes with right-mul)
  dim3 g1(Mpad / 128, 4);
  gemm_bt<<<g1, 256, 0, stream>>>(xb, W1b, y1b, K, 512);
  prop1_kernel<<<(Nn + 3) / 4, 256, 0, stream>>>(y1b, colA, rowp, cursor, dinv, b1,
                                                 embf, xb /* emb bf16, aliases xb */, Nn);

  // layer 2: z = emb @ W2^T (bf16), then propagate + b2
  u16t* zb = y1b;  // alias: y1 dead after prop1
  dim3 g2(Mpad / 128, 2);
  gemm_bt<<<g2, 256, 0, stream>>>(xb, W2b, zb, K, 256);
  prop2_kernel<<<(Nn + 3) / 4, 256, 0, stream>>>(zb, colA, rowp, cursor, dinv, b2, outf, Nn);
}